// Round 1
// baseline (108.883 us; speedup 1.0000x reference)
//
#include <hip/hip_runtime.h>
#include <hip/hip_fp16.h>

#define T    65536
#define TOUT 65532
#define NB   16
#define CH   32
#define NF   32
#define KS   5
#define BM   128

typedef _Float16 f16x8 __attribute__((ext_vector_type(8)));
typedef _Float16 f16x4 __attribute__((ext_vector_type(4)));
typedef float    f32x4 __attribute__((ext_vector_type(4)));

// ws layout: ws[0..31] = per-channel total sums of x; ws[32] = scalar s

// ---------------- Kernel 1: per-channel total sums of x ----------------
__global__ __launch_bounds__(256) void chsum_kernel(const float* __restrict__ x,
                                                    float* __restrict__ ws) {
    __shared__ float tot[CH];
    int tid = threadIdx.x;
    if (tid < CH) tot[tid] = 0.f;
    __syncthreads();
    size_t idx4   = (size_t)blockIdx.x * blockDim.x + tid;
    size_t n4     = (size_t)NB * T * CH / 4;
    size_t stride = (size_t)gridDim.x * blockDim.x;   // *4 floats % 32 == 0
    int c0 = (int)((idx4 * 4) & (CH - 1));            // constant across iters
    float s0 = 0.f, s1 = 0.f, s2 = 0.f, s3 = 0.f;
    const float4* x4 = (const float4*)x;
    for (size_t i = idx4; i < n4; i += stride) {
        float4 v = x4[i];
        s0 += v.x; s1 += v.y; s2 += v.z; s3 += v.w;
    }
    atomicAdd(&tot[c0 + 0], s0);
    atomicAdd(&tot[c0 + 1], s1);
    atomicAdd(&tot[c0 + 2], s2);
    atomicAdd(&tot[c0 + 3], s3);
    __syncthreads();
    if (tid < CH) atomicAdd(&ws[tid], tot[tid]);
}

// ---------------- Kernel 2: assemble mean(offset), compute s ----------------
__global__ __launch_bounds__(256) void scalar_kernel(const float* __restrict__ x,
                                                     const float* __restrict__ Wconv,
                                                     const float* __restrict__ bconv,
                                                     const float* __restrict__ Wdef,
                                                     float* __restrict__ ws) {
    __shared__ float hb[4][CH], tb[4][CH];
    __shared__ float partial[256];
    int tid = threadIdx.x;
    // head/tail per-channel edge sums (summed over batch)
    if (tid < 128) {
        int j = tid >> 5, c = tid & 31;
        float s = 0.f;
        for (int b = 0; b < NB; ++b) s += x[((size_t)b * T + j) * CH + c];
        hb[j][c] = s;
    } else {
        int p = tid - 128; int j = p >> 5, c = p & 31;
        float s = 0.f;
        for (int b = 0; b < NB; ++b) s += x[((size_t)b * T + (T - 4 + j)) * CH + c];
        tb[j][c] = s;
    }
    __syncthreads();
    // term(k,c) = (sum_f W[k,c,f]) * S_k[c]
    float term = 0.f;
    if (tid < KS * CH) {
        int k = tid >> 5, c = tid & 31;
        float wf = 0.f;
        const float* wp = &Wconv[(size_t)tid * NF];
        for (int f = 0; f < NF; ++f) wf += wp[f];
        float S = ws[c];                       // total sum for channel c
        for (int j = 0; j < k; ++j) S -= hb[j][c];
        for (int j = k; j < 4; ++j) S -= tb[j][c];
        term = wf * S;
    }
    partial[tid] = term;
    __syncthreads();
    for (int off = 128; off > 0; off >>= 1) {
        if (tid < off) partial[tid] += partial[tid + off];
        __syncthreads();
    }
    if (tid == 0) {
        float sum_b = 0.f;
        for (int f = 0; f < NF; ++f) sum_b += bconv[f];
        float mean_off = partial[0] / (float)((size_t)NB * TOUT * NF) + sum_b / (float)NF;
        float s = 0.f;
        for (int k = 0; k < KS; ++k) {
            float pn = mean_off + (float)(k - 2);
            float sc = fmaxf(0.f, 1.f - fabsf(pn));
            s += Wdef[k] * sc;
        }
        ws[CH] = s;
    }
}

// ---------------- Kernel 3: out = s * conv(x) + bconv via f16 MFMA ----------------
__global__ __launch_bounds__(256) void conv_kernel(const float* __restrict__ x,
                                                   const float* __restrict__ Wconv,
                                                   const float* __restrict__ bconv,
                                                   const float* __restrict__ ws,
                                                   float* __restrict__ out) {
    __shared__ _Float16 A[(BM + 4) * 40];    // x tile, rows padded to 40 halves (80 B)
    __shared__ _Float16 Wt[KS * CH * 40];    // [k][f][c], rows padded to 40

    int tid = threadIdx.x;
    int b   = blockIdx.y;
    int t0  = blockIdx.x * BM;

    // stage A: rows t0 .. t0+BM+3, 32 channels, f32 -> f16
    const int AROWS = BM + 4;
    {
        int c0 = (tid & 7) * 4;
        for (int r = (tid >> 3); r < AROWS; r += 32) {
            int t = t0 + r;
            float4 v = make_float4(0.f, 0.f, 0.f, 0.f);
            if (t < T) v = *(const float4*)&x[((size_t)b * T + t) * CH + c0];
            f16x4 h;
            h[0] = (_Float16)v.x; h[1] = (_Float16)v.y;
            h[2] = (_Float16)v.z; h[3] = (_Float16)v.w;
            *(f16x4*)&A[r * 40 + c0] = h;
        }
    }
    // stage Wt transposed: Wt[k][f][c] = Wconv[k][c][f]
    if (tid < KS * CH) {
        int k = tid >> 5, c = tid & 31;
        const float* wp = &Wconv[(size_t)tid * NF];
        for (int f = 0; f < NF; ++f)
            Wt[(k * CH + f) * 40 + c] = (_Float16)wp[f];
    }
    __syncthreads();

    int lane = tid & 63;
    int wave = tid >> 6;
    int rowbase = wave * 32;          // wave handles 32 output rows
    int lrow = lane & 15;
    int kgrp = lane >> 4;

    f32x4 acc00 = {}, acc01 = {}, acc10 = {}, acc11 = {};
#pragma unroll
    for (int kk = 0; kk < KS; ++kk) {
        // A frag: A[i][kap], i = lane&15, kap = 8*(lane>>4)+j  -> channel of row t+kk
        f16x8 a0 = *(const f16x8*)&A[(rowbase + lrow + kk) * 40 + kgrp * 8];
        f16x8 a1 = *(const f16x8*)&A[(rowbase + 16 + lrow + kk) * 40 + kgrp * 8];
        // B frag: B[kap][n], n = lane&15 (filter), kap = channel -> Wt[k][f][c]
        f16x8 b0 = *(const f16x8*)&Wt[(kk * CH + lrow) * 40 + kgrp * 8];
        f16x8 b1 = *(const f16x8*)&Wt[(kk * CH + 16 + lrow) * 40 + kgrp * 8];
        acc00 = __builtin_amdgcn_mfma_f32_16x16x32_f16(a0, b0, acc00, 0, 0, 0);
        acc01 = __builtin_amdgcn_mfma_f32_16x16x32_f16(a0, b1, acc01, 0, 0, 0);
        acc10 = __builtin_amdgcn_mfma_f32_16x16x32_f16(a1, b0, acc10, 0, 0, 0);
        acc11 = __builtin_amdgcn_mfma_f32_16x16x32_f16(a1, b1, acc11, 0, 0, 0);
    }

    float sv  = ws[CH];
    int col0  = lane & 15;
    float bc0 = bconv[col0], bc1 = bconv[col0 + 16];
    int rbase = rowbase + ((lane >> 4) << 2);   // C/D: row=(lane>>4)*4+reg, col=lane&15
#pragma unroll
    for (int reg = 0; reg < 4; ++reg) {
        int t = t0 + rbase + reg;
        if (t < TOUT) {
            float* o = &out[((size_t)b * TOUT + t) * NF];
            o[col0]      = sv * acc00[reg] + bc0;
            o[col0 + 16] = sv * acc01[reg] + bc1;
        }
        int t1 = t + 16;
        if (t1 < TOUT) {
            float* o = &out[((size_t)b * TOUT + t1) * NF];
            o[col0]      = sv * acc10[reg] + bc0;
            o[col0 + 16] = sv * acc11[reg] + bc1;
        }
    }
}

extern "C" void kernel_launch(void* const* d_in, const int* in_sizes, int n_in,
                              void* d_out, int out_size, void* d_ws, size_t ws_size,
                              hipStream_t stream) {
    const float* x     = (const float*)d_in[0];
    const float* Wconv = (const float*)d_in[1];
    const float* bconv = (const float*)d_in[2];
    const float* Wdef  = (const float*)d_in[3];
    float* out = (float*)d_out;
    float* ws  = (float*)d_ws;

    hipMemsetAsync(ws, 0, CH * sizeof(float), stream);      // zero Tot accumulators
    chsum_kernel<<<dim3(2048), dim3(256), 0, stream>>>(x, ws);
    scalar_kernel<<<dim3(1), dim3(256), 0, stream>>>(x, Wconv, bconv, Wdef, ws);
    dim3 grid((TOUT + BM - 1) / BM, NB);
    conv_kernel<<<grid, dim3(256), 0, stream>>>(x, Wconv, bconv, ws, out);
}

// Round 3
// 108.224 us; speedup vs baseline: 1.0061x; 1.0061x over previous
//
#include <hip/hip_runtime.h>
#include <hip/hip_fp16.h>
#include <hip/hip_cooperative_groups.h>

namespace cg = cooperative_groups;

#define T    65536
#define TOUT 65532
#define NB   16
#define CH   32
#define NF   32
#define KS   5
#define BM   128
#define RPB  1024      // rows of x owned per block (fused path)
#define NSUB 8         // RPB / BM
#define NBLK 1024      // 16 batches * 64 blocks

typedef _Float16 f16x8 __attribute__((ext_vector_type(8)));
typedef _Float16 f16x4 __attribute__((ext_vector_type(4)));
typedef float    f32x4 __attribute__((ext_vector_type(4)));

// ws layout: ws[0..31] = per-channel total sums of x; ws[32] = scalar s (fallback)

// ================= FUSED cooperative kernel (single read of x) =================
__global__ __launch_bounds__(256, 4) void fused_kernel(
    const float* __restrict__ x, const float* __restrict__ Wconv,
    const float* __restrict__ bconv, const float* __restrict__ Wdef,
    float* __restrict__ ws, float* __restrict__ out)
{
    __shared__ _Float16 A[(BM + 4) * 40];   // 132 rows, padded to 40 halves
    __shared__ _Float16 Wt[KS * CH * 40];   // [k][f][c], padded to 40
    __shared__ float tot[CH];
    __shared__ float hb[4][CH], tb[4][CH];
    __shared__ float partial[256];
    __shared__ float s_sh;

    const int tid = threadIdx.x;
    const int bid = blockIdx.x;
    const int b   = bid >> 6;               // 64 blocks per batch
    const int t0  = (bid & 63) * RPB;       // 64*1024 == T exactly
    const int c0  = (tid & 7) * 4;

    if (tid < KS * CH) {                    // Wt[k][f][c] = Wconv[k][c][f]
        const float* wp = &Wconv[(size_t)tid * NF];
        int k = tid >> 5, c = tid & 31;
        for (int f = 0; f < NF; ++f)
            Wt[(k * CH + f) * 40 + c] = (_Float16)wp[f];
    }
    if (tid < CH) tot[tid] = 0.f;
    __syncthreads();

    // ---- phase 1: stream owned region into registers (f16) + channel sums
    f16x4 st[NSUB][4];
    float s0 = 0.f, s1 = 0.f, s2 = 0.f, s3 = 0.f;
    const float4* xb = (const float4*)&x[((size_t)b * T + t0) * CH];
#pragma unroll
    for (int j = 0; j < NSUB; ++j) {
#pragma unroll
        for (int q = 0; q < 4; ++q) {
            float4 v = xb[j * 1024 + q * 256 + tid];
            s0 += v.x; s1 += v.y; s2 += v.z; s3 += v.w;
            f16x4 h;
            h[0] = (_Float16)v.x; h[1] = (_Float16)v.y;
            h[2] = (_Float16)v.z; h[3] = (_Float16)v.w;
            st[j][q] = h;
        }
    }
    atomicAdd(&tot[c0 + 0], s0);
    atomicAdd(&tot[c0 + 1], s1);
    atomicAdd(&tot[c0 + 2], s2);
    atomicAdd(&tot[c0 + 3], s3);
    __syncthreads();
    if (tid < CH) atomicAdd(&ws[tid], tot[tid]);
    __threadfence();

    cg::this_grid().sync();

    // ---- redundant scalar s per block (tiny, L2/L3-hot)
    {
        int j = tid >> 5, c = tid & 31;
        int row = (j < 4) ? j : (T - 8 + j);
        float e = 0.f;
        for (int bb = 0; bb < NB; ++bb)
            e += x[((size_t)bb * T + row) * CH + c];
        if (j < 4) hb[j][c] = e; else tb[j - 4][c] = e;
    }
    __syncthreads();
    float term = 0.f;
    if (tid < KS * CH) {
        int k = tid >> 5, c = tid & 31;
        float wf = 0.f;
        const float* wp = &Wconv[(size_t)tid * NF];
        for (int f = 0; f < NF; ++f) wf += wp[f];
        float S = __hip_atomic_load(&ws[c], __ATOMIC_RELAXED, __HIP_MEMORY_SCOPE_AGENT);
        for (int jj = 0; jj < k; ++jj) S -= hb[jj][c];
        for (int jj = k; jj < 4; ++jj) S -= tb[jj][c];
        term = wf * S;
    }
    partial[tid] = term;
    __syncthreads();
    for (int off = 128; off > 0; off >>= 1) {
        if (tid < off) partial[tid] += partial[tid + off];
        __syncthreads();
    }
    if (tid == 0) {
        float sum_b = 0.f;
        for (int f = 0; f < NF; ++f) sum_b += bconv[f];
        float mean_off = partial[0] / (float)((size_t)NB * TOUT * NF) + sum_b / (float)NF;
        float sv = 0.f;
        for (int k = 0; k < KS; ++k) {
            float pn = mean_off + (float)(k - 2);
            sv += Wdef[k] * fmaxf(0.f, 1.f - fabsf(pn));
        }
        s_sh = sv;
    }
    __syncthreads();

    const int lane    = tid & 63;
    const int wave    = tid >> 6;
    const int rowbase = wave * 32;
    const int lrow    = lane & 15;
    const int kgrp    = lane >> 4;
    const int col0    = lane & 15;
    const float sv    = s_sh;
    const float bc0   = bconv[col0], bc1 = bconv[col0 + 16];

    // ---- phase 2: per 128-row subtile, regs -> LDS -> MFMA -> scaled store
#pragma unroll
    for (int j = 0; j < NSUB; ++j) {
#pragma unroll
        for (int q = 0; q < 4; ++q) {
            int idx = q * 256 + tid;
            *(f16x4*)&A[(idx >> 3) * 40 + c0] = st[j][q];
        }
        if (tid < 32) {   // halo rows 128..131
            f16x4 h;
            if (j < NSUB - 1) {
                h = st[j + 1][0];
            } else {
                int t = t0 + RPB + (tid >> 3);
                float4 v = make_float4(0.f, 0.f, 0.f, 0.f);
                if (t < T) v = *(const float4*)&x[((size_t)b * T + t) * CH + c0];
                h[0] = (_Float16)v.x; h[1] = (_Float16)v.y;
                h[2] = (_Float16)v.z; h[3] = (_Float16)v.w;
            }
            *(f16x4*)&A[(128 + (tid >> 3)) * 40 + c0] = h;
        }
        __syncthreads();

        f32x4 acc00 = {}, acc01 = {}, acc10 = {}, acc11 = {};
#pragma unroll
        for (int kk = 0; kk < KS; ++kk) {
            f16x8 a0 = *(const f16x8*)&A[(rowbase + lrow + kk) * 40 + kgrp * 8];
            f16x8 a1 = *(const f16x8*)&A[(rowbase + 16 + lrow + kk) * 40 + kgrp * 8];
            f16x8 b0 = *(const f16x8*)&Wt[(kk * CH + lrow) * 40 + kgrp * 8];
            f16x8 b1 = *(const f16x8*)&Wt[(kk * CH + 16 + lrow) * 40 + kgrp * 8];
            acc00 = __builtin_amdgcn_mfma_f32_16x16x32_f16(a0, b0, acc00, 0, 0, 0);
            acc01 = __builtin_amdgcn_mfma_f32_16x16x32_f16(a0, b1, acc01, 0, 0, 0);
            acc10 = __builtin_amdgcn_mfma_f32_16x16x32_f16(a1, b0, acc10, 0, 0, 0);
            acc11 = __builtin_amdgcn_mfma_f32_16x16x32_f16(a1, b1, acc11, 0, 0, 0);
        }

        int tsub  = t0 + j * BM;
        int rbase = rowbase + ((lane >> 4) << 2);
#pragma unroll
        for (int reg = 0; reg < 4; ++reg) {
            int t = tsub + rbase + reg;
            if (t < TOUT) {
                float* o = &out[((size_t)b * TOUT + t) * NF];
                o[col0]      = sv * acc00[reg] + bc0;
                o[col0 + 16] = sv * acc01[reg] + bc1;
            }
            int t1 = t + 16;
            if (t1 < TOUT) {
                float* o = &out[((size_t)b * TOUT + t1) * NF];
                o[col0]      = sv * acc10[reg] + bc0;
                o[col0 + 16] = sv * acc11[reg] + bc1;
            }
        }
        __syncthreads();
    }
}

// ================= FALLBACK path (round-1, proven) =================
__global__ __launch_bounds__(256) void chsum_kernel(const float* __restrict__ x,
                                                    float* __restrict__ ws) {
    __shared__ float tot[CH];
    int tid = threadIdx.x;
    if (tid < CH) tot[tid] = 0.f;
    __syncthreads();
    size_t idx4   = (size_t)blockIdx.x * blockDim.x + tid;
    size_t n4     = (size_t)NB * T * CH / 4;
    size_t stride = (size_t)gridDim.x * blockDim.x;
    int c0 = (int)((idx4 * 4) & (CH - 1));
    float s0 = 0.f, s1 = 0.f, s2 = 0.f, s3 = 0.f;
    const float4* x4 = (const float4*)x;
    for (size_t i = idx4; i < n4; i += stride) {
        float4 v = x4[i];
        s0 += v.x; s1 += v.y; s2 += v.z; s3 += v.w;
    }
    atomicAdd(&tot[c0 + 0], s0);
    atomicAdd(&tot[c0 + 1], s1);
    atomicAdd(&tot[c0 + 2], s2);
    atomicAdd(&tot[c0 + 3], s3);
    __syncthreads();
    if (tid < CH) atomicAdd(&ws[tid], tot[tid]);
}

__global__ __launch_bounds__(256) void scalar_kernel(const float* __restrict__ x,
                                                     const float* __restrict__ Wconv,
                                                     const float* __restrict__ bconv,
                                                     const float* __restrict__ Wdef,
                                                     float* __restrict__ ws) {
    __shared__ float hb[4][CH], tb[4][CH];
    __shared__ float partial[256];
    int tid = threadIdx.x;
    if (tid < 128) {
        int j = tid >> 5, c = tid & 31;
        float s = 0.f;
        for (int b = 0; b < NB; ++b) s += x[((size_t)b * T + j) * CH + c];
        hb[j][c] = s;
    } else {
        int p = tid - 128; int j = p >> 5, c = p & 31;
        float s = 0.f;
        for (int b = 0; b < NB; ++b) s += x[((size_t)b * T + (T - 4 + j)) * CH + c];
        tb[j][c] = s;
    }
    __syncthreads();
    float term = 0.f;
    if (tid < KS * CH) {
        int k = tid >> 5, c = tid & 31;
        float wf = 0.f;
        const float* wp = &Wconv[(size_t)tid * NF];
        for (int f = 0; f < NF; ++f) wf += wp[f];
        float S = ws[c];
        for (int j = 0; j < k; ++j) S -= hb[j][c];
        for (int j = k; j < 4; ++j) S -= tb[j][c];
        term = wf * S;
    }
    partial[tid] = term;
    __syncthreads();
    for (int off = 128; off > 0; off >>= 1) {
        if (tid < off) partial[tid] += partial[tid + off];
        __syncthreads();
    }
    if (tid == 0) {
        float sum_b = 0.f;
        for (int f = 0; f < NF; ++f) sum_b += bconv[f];
        float mean_off = partial[0] / (float)((size_t)NB * TOUT * NF) + sum_b / (float)NF;
        float s = 0.f;
        for (int k = 0; k < KS; ++k) {
            float pn = mean_off + (float)(k - 2);
            s += Wdef[k] * fmaxf(0.f, 1.f - fabsf(pn));
        }
        ws[CH] = s;
    }
}

__global__ __launch_bounds__(256) void conv_kernel(const float* __restrict__ x,
                                                   const float* __restrict__ Wconv,
                                                   const float* __restrict__ bconv,
                                                   const float* __restrict__ ws,
                                                   float* __restrict__ out) {
    __shared__ _Float16 A[(BM + 4) * 40];
    __shared__ _Float16 Wt[KS * CH * 40];

    int tid = threadIdx.x;
    int b   = blockIdx.y;
    int t0  = blockIdx.x * BM;

    const int AROWS = BM + 4;
    {
        int c0 = (tid & 7) * 4;
        for (int r = (tid >> 3); r < AROWS; r += 32) {
            int t = t0 + r;
            float4 v = make_float4(0.f, 0.f, 0.f, 0.f);
            if (t < T) v = *(const float4*)&x[((size_t)b * T + t) * CH + c0];
            f16x4 h;
            h[0] = (_Float16)v.x; h[1] = (_Float16)v.y;
            h[2] = (_Float16)v.z; h[3] = (_Float16)v.w;
            *(f16x4*)&A[r * 40 + c0] = h;
        }
    }
    if (tid < KS * CH) {
        int k = tid >> 5, c = tid & 31;
        const float* wp = &Wconv[(size_t)tid * NF];
        for (int f = 0; f < NF; ++f)
            Wt[(k * CH + f) * 40 + c] = (_Float16)wp[f];
    }
    __syncthreads();

    int lane = tid & 63;
    int wave = tid >> 6;
    int rowbase = wave * 32;
    int lrow = lane & 15;
    int kgrp = lane >> 4;

    f32x4 acc00 = {}, acc01 = {}, acc10 = {}, acc11 = {};
#pragma unroll
    for (int kk = 0; kk < KS; ++kk) {
        f16x8 a0 = *(const f16x8*)&A[(rowbase + lrow + kk) * 40 + kgrp * 8];
        f16x8 a1 = *(const f16x8*)&A[(rowbase + 16 + lrow + kk) * 40 + kgrp * 8];
        f16x8 b0 = *(const f16x8*)&Wt[(kk * CH + lrow) * 40 + kgrp * 8];
        f16x8 b1 = *(const f16x8*)&Wt[(kk * CH + 16 + lrow) * 40 + kgrp * 8];
        acc00 = __builtin_amdgcn_mfma_f32_16x16x32_f16(a0, b0, acc00, 0, 0, 0);
        acc01 = __builtin_amdgcn_mfma_f32_16x16x32_f16(a0, b1, acc01, 0, 0, 0);
        acc10 = __builtin_amdgcn_mfma_f32_16x16x32_f16(a1, b0, acc10, 0, 0, 0);
        acc11 = __builtin_amdgcn_mfma_f32_16x16x32_f16(a1, b1, acc11, 0, 0, 0);
    }

    float sv  = ws[CH];
    int col0  = lane & 15;
    float bc0 = bconv[col0], bc1 = bconv[col0 + 16];
    int rbase = rowbase + ((lane >> 4) << 2);
#pragma unroll
    for (int reg = 0; reg < 4; ++reg) {
        int t = t0 + rbase + reg;
        if (t < TOUT) {
            float* o = &out[((size_t)b * TOUT + t) * NF];
            o[col0]      = sv * acc00[reg] + bc0;
            o[col0 + 16] = sv * acc01[reg] + bc1;
        }
        int t1 = t + 16;
        if (t1 < TOUT) {
            float* o = &out[((size_t)b * TOUT + t1) * NF];
            o[col0]      = sv * acc10[reg] + bc0;
            o[col0 + 16] = sv * acc11[reg] + bc1;
        }
    }
}

static void launch_fallback(const float* x, const float* Wconv, const float* bconv,
                            const float* Wdef, float* ws, float* out, hipStream_t stream) {
    chsum_kernel<<<dim3(2048), dim3(256), 0, stream>>>(x, ws);
    scalar_kernel<<<dim3(1), dim3(256), 0, stream>>>(x, Wconv, bconv, Wdef, ws);
    dim3 grid((TOUT + BM - 1) / BM, NB);
    conv_kernel<<<grid, dim3(256), 0, stream>>>(x, Wconv, bconv, ws, out);
}

extern "C" void kernel_launch(void* const* d_in, const int* in_sizes, int n_in,
                              void* d_out, int out_size, void* d_ws, size_t ws_size,
                              hipStream_t stream) {
    const float* x     = (const float*)d_in[0];
    const float* Wconv = (const float*)d_in[1];
    const float* bconv = (const float*)d_in[2];
    const float* Wdef  = (const float*)d_in[3];
    float* out = (float*)d_out;
    float* ws  = (float*)d_ws;

    hipMemsetAsync(ws, 0, 64 * sizeof(float), stream);   // zero sum accumulators

    // Host-side, capture-safe gating for the cooperative path.
    int dev = 0, coop = 0, nb = 0;
    (void)hipGetDevice(&dev);
    (void)hipDeviceGetAttribute(&coop, hipDeviceAttributeCooperativeLaunch, dev);
    (void)hipOccupancyMaxActiveBlocksPerMultiprocessor(&nb, fused_kernel, 256, 0);

    bool done = false;
    if (coop && nb >= 4) {   // 4 blocks/CU * 256 CUs >= NBLK => co-residency guaranteed
        void* args[] = { (void*)&x, (void*)&Wconv, (void*)&bconv, (void*)&Wdef,
                         (void*)&ws, (void*)&out };
        hipError_t e = hipLaunchCooperativeKernel((void*)fused_kernel, dim3(NBLK),
                                                  dim3(256), args, 0, stream);
        done = (e == hipSuccess);
    }
    if (!done) launch_fallback(x, Wconv, bconv, Wdef, ws, out, stream);
}

// Round 4
// 108.166 us; speedup vs baseline: 1.0066x; 1.0005x over previous
//
#include <hip/hip_runtime.h>
#include <hip/hip_fp16.h>

#define T     65536
#define TOUT  65532
#define NB    16
#define CH    32
#define NF    32
#define KS    5
#define BM    128      // fallback conv tile
#define NBLKM 1024     // mono grid: 4 blocks/CU * 256 CU

typedef _Float16 f16x8 __attribute__((ext_vector_type(8)));
typedef _Float16 f16x4 __attribute__((ext_vector_type(4)));
typedef float    f32x4 __attribute__((ext_vector_type(4)));

// ws layout: ws[0..31] = per-channel sums; ((uint*)ws)[32] = barrier counter;
//            ws[33] (as float, index CH in fallback path) handled separately:
//            fallback uses ws[32] for s -> keep mono counter at uint index 40.
// To be safe, mono counter lives at ((unsigned int*)ws)[40] (byte 160).
// memset zeroes first 256 bytes each call.

// ===================== MONO kernel (spin-barrier, single x read) =====================
__global__ __launch_bounds__(256, 4) void mono_kernel(
    const float* __restrict__ x, const float* __restrict__ Wconv,
    const float* __restrict__ bconv, const float* __restrict__ Wdef,
    float* __restrict__ ws, float* __restrict__ out)
{
    __shared__ _Float16 Wt[KS * CH * 40];   // [k][f][c], rows padded to 40 halves
    __shared__ float tot[CH];
    __shared__ float hb[4][CH], tb[4][CH];
    __shared__ float partial[256];
    __shared__ float s_sh;

    const int tid = threadIdx.x;
    const int bid = blockIdx.x;

    if (tid < KS * CH) {                    // Wt[k][f][c] = Wconv[k][c][f]
        int k = tid >> 5, c = tid & 31;
        const float* wp = &Wconv[(size_t)tid * NF];
        for (int f = 0; f < NF; ++f)
            Wt[(k * CH + f) * 40 + c] = (_Float16)wp[f];
    }
    if (tid < CH) tot[tid] = 0.f;
    __syncthreads();

    // ---- phase 1: per-block contiguous chunk, per-channel sums ----
    {
        const float4* x4 = (const float4*)x;
        size_t base = (size_t)bid * 8192;          // 8192 float4 per block
        float s0 = 0.f, s1 = 0.f, s2 = 0.f, s3 = 0.f;
#pragma unroll 8
        for (int q = 0; q < 32; ++q) {
            float4 v = x4[base + (size_t)q * 256 + tid];
            s0 += v.x; s1 += v.y; s2 += v.z; s3 += v.w;
        }
        int c0 = (tid & 7) * 4;
        atomicAdd(&tot[c0 + 0], s0);
        atomicAdd(&tot[c0 + 1], s1);
        atomicAdd(&tot[c0 + 2], s2);
        atomicAdd(&tot[c0 + 3], s3);
    }
    __syncthreads();
    if (tid < CH) {
        // returning release atomic: completion guaranteed before we pass barrier
        float old = __hip_atomic_fetch_add(&ws[tid], tot[tid],
                                           __ATOMIC_RELEASE, __HIP_MEMORY_SCOPE_AGENT);
        asm volatile("" :: "v"(old));   // keep the returned value -> forces wait
    }
    __syncthreads();

    // ---- device-wide spin barrier ----
    {
        unsigned int* cnt = (unsigned int*)ws + 40;
        if (tid == 0) {
            __hip_atomic_fetch_add(cnt, 1u, __ATOMIC_ACQ_REL, __HIP_MEMORY_SCOPE_AGENT);
            unsigned int guard = 0;
            while (__hip_atomic_load(cnt, __ATOMIC_ACQUIRE, __HIP_MEMORY_SCOPE_AGENT)
                       < (unsigned)NBLKM) {
                __builtin_amdgcn_s_sleep(8);
                if (++guard > (1u << 27)) break;   // anti-hang insurance
            }
        }
        __syncthreads();
    }

    // ---- redundant scalar s per block (tiny, L3-hot) ----
    {
        int j = tid >> 5, c = tid & 31;            // j in 0..7
        int row = (j < 4) ? j : (T - 8 + j);
        float e = 0.f;
        for (int bb = 0; bb < NB; ++bb)
            e += x[((size_t)bb * T + row) * CH + c];
        if (j < 4) hb[j][c] = e; else tb[j - 4][c] = e;
    }
    __syncthreads();
    float term = 0.f;
    if (tid < KS * CH) {
        int k = tid >> 5, c = tid & 31;
        float wf = 0.f;
        const float* wp = &Wconv[(size_t)tid * NF];
        for (int f = 0; f < NF; ++f) wf += wp[f];
        float S = __hip_atomic_load(&ws[c], __ATOMIC_RELAXED, __HIP_MEMORY_SCOPE_AGENT);
        for (int jj = 0; jj < k; ++jj) S -= hb[jj][c];
        for (int jj = k; jj < 4; ++jj) S -= tb[jj][c];
        term = wf * S;
    }
    partial[tid] = term;
    __syncthreads();
    for (int off = 128; off > 0; off >>= 1) {
        if (tid < off) partial[tid] += partial[tid + off];
        __syncthreads();
    }
    if (tid == 0) {
        float sum_b = 0.f;
        for (int f = 0; f < NF; ++f) sum_b += bconv[f];
        float mean_off = partial[0] / (float)((size_t)NB * TOUT * NF) + sum_b / (float)NF;
        float sv = 0.f;
        for (int k = 0; k < KS; ++k) {
            float pn = mean_off + (float)(k - 2);
            sv += Wdef[k] * fmaxf(0.f, 1.f - fabsf(pn));
        }
        s_sh = sv;
    }
    __syncthreads();

    // ---- phase 2: conv via direct-global A-frags (x is L3/L2-hot) ----
    const int lane = tid & 63;
    const int wave = tid >> 6;
    const int lrow = lane & 15;
    const int kgrp = lane >> 4;
    const int col0 = lane & 15;
    const float sv  = s_sh;
    const float bc0 = bconv[col0], bc1 = bconv[col0 + 16];

    // B-frags from LDS once: bf[kk][cg]
    f16x8 bf[KS][2];
#pragma unroll
    for (int kk = 0; kk < KS; ++kk) {
        bf[kk][0] = *(const f16x8*)&Wt[(kk * CH + lrow) * 40 + kgrp * 8];
        bf[kk][1] = *(const f16x8*)&Wt[(kk * CH + 16 + lrow) * 40 + kgrp * 8];
    }

    const int b  = bid >> 6;                       // 64 blocks per batch
    const int tb0 = (bid & 63) * 1024;             // block's 1024-row region
    const float* xb = x + (size_t)b * T * CH;

#pragma unroll 1
    for (int tile = 0; tile < 4; ++tile) {         // 4 tiles of 256 rows
        int rs = tb0 + tile * 256 + wave * 64;     // this wave's 64-row strip

        f32x4 acc[4][2];
#pragma unroll
        for (int rg = 0; rg < 4; ++rg) { acc[rg][0] = (f32x4){}; acc[rg][1] = (f32x4){}; }

#pragma unroll
        for (int rg = 0; rg < 4; ++rg) {
#pragma unroll
            for (int kk = 0; kk < KS; ++kk) {
                int trow = rs + rg * 16 + lrow + kk;
                trow = (trow < T - 1) ? trow : (T - 1);      // clamp (stores predicated)
                const float* xr = xb + (size_t)trow * CH + (kgrp << 3);
                float4 lo = *(const float4*)xr;
                float4 hi = *(const float4*)(xr + 4);
                f16x8 af;
                af[0] = (_Float16)lo.x; af[1] = (_Float16)lo.y;
                af[2] = (_Float16)lo.z; af[3] = (_Float16)lo.w;
                af[4] = (_Float16)hi.x; af[5] = (_Float16)hi.y;
                af[6] = (_Float16)hi.z; af[7] = (_Float16)hi.w;
                acc[rg][0] = __builtin_amdgcn_mfma_f32_16x16x32_f16(af, bf[kk][0], acc[rg][0], 0, 0, 0);
                acc[rg][1] = __builtin_amdgcn_mfma_f32_16x16x32_f16(af, bf[kk][1], acc[rg][1], 0, 0, 0);
            }
        }

#pragma unroll
        for (int rg = 0; rg < 4; ++rg) {
            int rb = rs + rg * 16 + ((lane >> 4) << 2);
#pragma unroll
            for (int reg = 0; reg < 4; ++reg) {
                int r = rb + reg;
                if (r < TOUT) {
                    float* o = &out[((size_t)b * TOUT + r) * NF];
                    o[col0]      = sv * acc[rg][0][reg] + bc0;
                    o[col0 + 16] = sv * acc[rg][1][reg] + bc1;
                }
            }
        }
    }
}

// ===================== FALLBACK path (round-1, proven 108 µs) =====================
__global__ __launch_bounds__(256) void chsum_kernel(const float* __restrict__ x,
                                                    float* __restrict__ ws) {
    __shared__ float tot[CH];
    int tid = threadIdx.x;
    if (tid < CH) tot[tid] = 0.f;
    __syncthreads();
    size_t idx4   = (size_t)blockIdx.x * blockDim.x + tid;
    size_t n4     = (size_t)NB * T * CH / 4;
    size_t stride = (size_t)gridDim.x * blockDim.x;
    int c0 = (int)((idx4 * 4) & (CH - 1));
    float s0 = 0.f, s1 = 0.f, s2 = 0.f, s3 = 0.f;
    const float4* x4 = (const float4*)x;
    for (size_t i = idx4; i < n4; i += stride) {
        float4 v = x4[i];
        s0 += v.x; s1 += v.y; s2 += v.z; s3 += v.w;
    }
    atomicAdd(&tot[c0 + 0], s0);
    atomicAdd(&tot[c0 + 1], s1);
    atomicAdd(&tot[c0 + 2], s2);
    atomicAdd(&tot[c0 + 3], s3);
    __syncthreads();
    if (tid < CH) atomicAdd(&ws[tid], tot[tid]);
}

__global__ __launch_bounds__(256) void scalar_kernel(const float* __restrict__ x,
                                                     const float* __restrict__ Wconv,
                                                     const float* __restrict__ bconv,
                                                     const float* __restrict__ Wdef,
                                                     float* __restrict__ ws) {
    __shared__ float hb[4][CH], tb[4][CH];
    __shared__ float partial[256];
    int tid = threadIdx.x;
    if (tid < 128) {
        int j = tid >> 5, c = tid & 31;
        float s = 0.f;
        for (int b = 0; b < NB; ++b) s += x[((size_t)b * T + j) * CH + c];
        hb[j][c] = s;
    } else {
        int p = tid - 128; int j = p >> 5, c = p & 31;
        float s = 0.f;
        for (int b = 0; b < NB; ++b) s += x[((size_t)b * T + (T - 4 + j)) * CH + c];
        tb[j][c] = s;
    }
    __syncthreads();
    float term = 0.f;
    if (tid < KS * CH) {
        int k = tid >> 5, c = tid & 31;
        float wf = 0.f;
        const float* wp = &Wconv[(size_t)tid * NF];
        for (int f = 0; f < NF; ++f) wf += wp[f];
        float S = ws[c];
        for (int j = 0; j < k; ++j) S -= hb[j][c];
        for (int j = k; j < 4; ++j) S -= tb[j][c];
        term = wf * S;
    }
    partial[tid] = term;
    __syncthreads();
    for (int off = 128; off > 0; off >>= 1) {
        if (tid < off) partial[tid] += partial[tid + off];
        __syncthreads();
    }
    if (tid == 0) {
        float sum_b = 0.f;
        for (int f = 0; f < NF; ++f) sum_b += bconv[f];
        float mean_off = partial[0] / (float)((size_t)NB * TOUT * NF) + sum_b / (float)NF;
        float s = 0.f;
        for (int k = 0; k < KS; ++k) {
            float pn = mean_off + (float)(k - 2);
            s += Wdef[k] * fmaxf(0.f, 1.f - fabsf(pn));
        }
        ws[CH] = s;
    }
}

__global__ __launch_bounds__(256) void conv_kernel(const float* __restrict__ x,
                                                   const float* __restrict__ Wconv,
                                                   const float* __restrict__ bconv,
                                                   const float* __restrict__ ws,
                                                   float* __restrict__ out) {
    __shared__ _Float16 A[(BM + 4) * 40];
    __shared__ _Float16 Wt[KS * CH * 40];

    int tid = threadIdx.x;
    int b   = blockIdx.y;
    int t0  = blockIdx.x * BM;

    const int AROWS = BM + 4;
    {
        int c0 = (tid & 7) * 4;
        for (int r = (tid >> 3); r < AROWS; r += 32) {
            int t = t0 + r;
            float4 v = make_float4(0.f, 0.f, 0.f, 0.f);
            if (t < T) v = *(const float4*)&x[((size_t)b * T + t) * CH + c0];
            f16x4 h;
            h[0] = (_Float16)v.x; h[1] = (_Float16)v.y;
            h[2] = (_Float16)v.z; h[3] = (_Float16)v.w;
            *(f16x4*)&A[r * 40 + c0] = h;
        }
    }
    if (tid < KS * CH) {
        int k = tid >> 5, c = tid & 31;
        const float* wp = &Wconv[(size_t)tid * NF];
        for (int f = 0; f < NF; ++f)
            Wt[(k * CH + f) * 40 + c] = (_Float16)wp[f];
    }
    __syncthreads();

    int lane = tid & 63;
    int wave = tid >> 6;
    int rowbase = wave * 32;
    int lrow = lane & 15;
    int kgrp = lane >> 4;

    f32x4 acc00 = {}, acc01 = {}, acc10 = {}, acc11 = {};
#pragma unroll
    for (int kk = 0; kk < KS; ++kk) {
        f16x8 a0 = *(const f16x8*)&A[(rowbase + lrow + kk) * 40 + kgrp * 8];
        f16x8 a1 = *(const f16x8*)&A[(rowbase + 16 + lrow + kk) * 40 + kgrp * 8];
        f16x8 b0 = *(const f16x8*)&Wt[(kk * CH + lrow) * 40 + kgrp * 8];
        f16x8 b1 = *(const f16x8*)&Wt[(kk * CH + 16 + lrow) * 40 + kgrp * 8];
        acc00 = __builtin_amdgcn_mfma_f32_16x16x32_f16(a0, b0, acc00, 0, 0, 0);
        acc01 = __builtin_amdgcn_mfma_f32_16x16x32_f16(a0, b1, acc01, 0, 0, 0);
        acc10 = __builtin_amdgcn_mfma_f32_16x16x32_f16(a1, b0, acc10, 0, 0, 0);
        acc11 = __builtin_amdgcn_mfma_f32_16x16x32_f16(a1, b1, acc11, 0, 0, 0);
    }

    float sv  = ws[CH];
    int col0  = lane & 15;
    float bc0 = bconv[col0], bc1 = bconv[col0 + 16];
    int rbase = rowbase + ((lane >> 4) << 2);
#pragma unroll
    for (int reg = 0; reg < 4; ++reg) {
        int t = t0 + rbase + reg;
        if (t < TOUT) {
            float* o = &out[((size_t)b * TOUT + t) * NF];
            o[col0]      = sv * acc00[reg] + bc0;
            o[col0 + 16] = sv * acc01[reg] + bc1;
        }
        int t1 = t + 16;
        if (t1 < TOUT) {
            float* o = &out[((size_t)b * TOUT + t1) * NF];
            o[col0]      = sv * acc10[reg] + bc0;
            o[col0 + 16] = sv * acc11[reg] + bc1;
        }
    }
}

extern "C" void kernel_launch(void* const* d_in, const int* in_sizes, int n_in,
                              void* d_out, int out_size, void* d_ws, size_t ws_size,
                              hipStream_t stream) {
    const float* x     = (const float*)d_in[0];
    const float* Wconv = (const float*)d_in[1];
    const float* bconv = (const float*)d_in[2];
    const float* Wdef  = (const float*)d_in[3];
    float* out = (float*)d_out;
    float* ws  = (float*)d_ws;

    hipMemsetAsync(ws, 0, 256, stream);   // sums + counter zeroed every call

    int nb = 0;
    (void)hipOccupancyMaxActiveBlocksPerMultiprocessor(&nb, mono_kernel, 256, 0);

    if (nb >= 4) {
        // 4 blocks/CU * 256 CU = 1024 -> all NBLKM blocks co-resident; spin barrier safe
        mono_kernel<<<dim3(NBLKM), dim3(256), 0, stream>>>(x, Wconv, bconv, Wdef, ws, out);
    } else {
        chsum_kernel<<<dim3(2048), dim3(256), 0, stream>>>(x, ws);
        scalar_kernel<<<dim3(1), dim3(256), 0, stream>>>(x, Wconv, bconv, Wdef, ws);
        dim3 grid((TOUT + BM - 1) / BM, NB);
        conv_kernel<<<grid, dim3(256), 0, stream>>>(x, Wconv, bconv, ws, out);
    }
}

// Round 5
// 108.144 us; speedup vs baseline: 1.0068x; 1.0002x over previous
//
#include <hip/hip_runtime.h>
#include <hip/hip_fp16.h>

#define T     65536
#define TOUT  65532
#define NB    16
#define CH    32
#define NF    32
#define KS    5
#define BM    128      // conv subtile rows
#define NBLKM 1024     // mono grid: 4 blocks/CU * 256 CU
#define RPB   1024     // rows per block (mono)

typedef _Float16 f16x8 __attribute__((ext_vector_type(8)));
typedef _Float16 f16x4 __attribute__((ext_vector_type(4)));
typedef float    f32x4 __attribute__((ext_vector_type(4)));

// ws: ws[0..31] = per-channel sums; ws[32] = s (fallback); uint idx 40 = mono barrier counter

__device__ __forceinline__ f16x4 cvt4(float4 v) {
    f16x4 h;
    h[0] = (_Float16)v.x; h[1] = (_Float16)v.y;
    h[2] = (_Float16)v.z; h[3] = (_Float16)v.w;
    return h;
}

// ===================== MONO v2: single x read + LDS-staged pipelined conv =====================
__global__ __launch_bounds__(256, 4) void mono2_kernel(
    const float* __restrict__ x, const float* __restrict__ Wconv,
    const float* __restrict__ bconv, const float* __restrict__ Wdef,
    float* __restrict__ ws, float* __restrict__ out)
{
    __shared__ _Float16 A[(BM + 4) * 40];   // 132 rows, rows padded to 40 halves
    __shared__ _Float16 Wt[KS * CH * 40];   // [k][f][c]
    __shared__ float tot[CH];
    __shared__ float hb[4][CH], tb[4][CH];
    __shared__ float partial[256];
    __shared__ float s_sh;

    const int tid = threadIdx.x;
    const int bid = blockIdx.x;
    const int b   = bid >> 6;               // 64 blocks per batch
    const int tb0 = (bid & 63) * RPB;
    const int c0  = (tid & 7) * 4;
    const float* xb = x + (size_t)b * T * CH;

    if (tid < KS * CH) {                    // Wt[k][f][c] = Wconv[k][c][f]
        int k = tid >> 5, c = tid & 31;
        const float* wp = &Wconv[(size_t)tid * NF];
        for (int f = 0; f < NF; ++f)
            Wt[(k * CH + f) * 40 + c] = (_Float16)wp[f];
    }
    if (tid < CH) tot[tid] = 0.f;
    __syncthreads();

    // ---- phase 1: per-channel sums of own 1024-row region ----
    {
        const float4* x4 = (const float4*)x;
        size_t base = (size_t)bid * 8192;
        float s0 = 0.f, s1 = 0.f, s2 = 0.f, s3 = 0.f;
#pragma unroll 8
        for (int q = 0; q < 32; ++q) {
            float4 v = x4[base + (size_t)q * 256 + tid];
            s0 += v.x; s1 += v.y; s2 += v.z; s3 += v.w;
        }
        atomicAdd(&tot[c0 + 0], s0);
        atomicAdd(&tot[c0 + 1], s1);
        atomicAdd(&tot[c0 + 2], s2);
        atomicAdd(&tot[c0 + 3], s3);
    }
    __syncthreads();
    if (tid < CH) {
        float old = __hip_atomic_fetch_add(&ws[tid], tot[tid],
                                           __ATOMIC_RELEASE, __HIP_MEMORY_SCOPE_AGENT);
        asm volatile("" :: "v"(old));
    }
    __syncthreads();

    // ---- staging register buffers + loaders (T14: issue early, write late) ----
    float4 rv0, rv1, rv2, rv3, rvh;
    const int srow = tid >> 3;              // 0..31
    auto LOADJ = [&](int j) {
        const float* p = xb + (size_t)(tb0 + j * BM + srow) * CH + c0;
        rv0 = *(const float4*)(p);
        rv1 = *(const float4*)(p + 32 * CH);
        rv2 = *(const float4*)(p + 64 * CH);
        rv3 = *(const float4*)(p + 96 * CH);
        if (tid < 32) {
            int t = tb0 + j * BM + 128 + srow;
            rvh = (t < T) ? *(const float4*)(xb + (size_t)t * CH + c0)
                          : make_float4(0.f, 0.f, 0.f, 0.f);
        }
    };
    auto WRITEJ = [&]() {
        *(f16x4*)&A[(srow     ) * 40 + c0] = cvt4(rv0);
        *(f16x4*)&A[(srow + 32) * 40 + c0] = cvt4(rv1);
        *(f16x4*)&A[(srow + 64) * 40 + c0] = cvt4(rv2);
        *(f16x4*)&A[(srow + 96) * 40 + c0] = cvt4(rv3);
        if (tid < 32)
            *(f16x4*)&A[(128 + srow) * 40 + c0] = cvt4(rvh);
    };

    LOADJ(0);   // in flight across the spin barrier + scalar section

    // ---- device-wide spin barrier ----
    {
        unsigned int* cnt = (unsigned int*)ws + 40;
        if (tid == 0) {
            __hip_atomic_fetch_add(cnt, 1u, __ATOMIC_ACQ_REL, __HIP_MEMORY_SCOPE_AGENT);
            unsigned int guard = 0;
            while (__hip_atomic_load(cnt, __ATOMIC_ACQUIRE, __HIP_MEMORY_SCOPE_AGENT)
                       < (unsigned)NBLKM) {
                __builtin_amdgcn_s_sleep(8);
                if (++guard > (1u << 27)) break;
            }
        }
        __syncthreads();
    }

    // ---- redundant scalar s (tiny, L3-hot) ----
    {
        int j = tid >> 5, c = tid & 31;
        int row = (j < 4) ? j : (T - 8 + j);
        float e = 0.f;
        for (int bb = 0; bb < NB; ++bb)
            e += x[((size_t)bb * T + row) * CH + c];
        if (j < 4) hb[j][c] = e; else tb[j - 4][c] = e;
    }
    __syncthreads();
    float term = 0.f;
    if (tid < KS * CH) {
        int k = tid >> 5, c = tid & 31;
        float wf = 0.f;
        const float* wp = &Wconv[(size_t)tid * NF];
        for (int f = 0; f < NF; ++f) wf += wp[f];
        float S = __hip_atomic_load(&ws[c], __ATOMIC_RELAXED, __HIP_MEMORY_SCOPE_AGENT);
        for (int jj = 0; jj < k; ++jj) S -= hb[jj][c];
        for (int jj = k; jj < 4; ++jj) S -= tb[jj][c];
        term = wf * S;
    }
    partial[tid] = term;
    __syncthreads();
    for (int off = 128; off > 0; off >>= 1) {
        if (tid < off) partial[tid] += partial[tid + off];
        __syncthreads();
    }
    if (tid == 0) {
        float sum_b = 0.f;
        for (int f = 0; f < NF; ++f) sum_b += bconv[f];
        float mean_off = partial[0] / (float)((size_t)NB * TOUT * NF) + sum_b / (float)NF;
        float sv = 0.f;
        for (int k = 0; k < KS; ++k) {
            float pn = mean_off + (float)(k - 2);
            sv += Wdef[k] * fmaxf(0.f, 1.f - fabsf(pn));
        }
        s_sh = sv;
    }
    __syncthreads();

    // ---- phase 2: 8 subtiles, software-pipelined LDS-staged MFMA conv ----
    const int lane    = tid & 63;
    const int wave    = tid >> 6;
    const int rowbase = wave * 32;
    const int lrow    = lane & 15;
    const int kgrp    = lane >> 4;
    const int col0    = lane & 15;
    const float sv    = s_sh;
    const float bc0   = bconv[col0], bc1 = bconv[col0 + 16];

#pragma unroll
    for (int j = 0; j < 8; ++j) {
        __syncthreads();                 // previous subtile's MFMA reads of A done
        WRITEJ();
        if (j < 7) LOADJ(j + 1);         // next loads in flight under barrier+MFMA+store
        __syncthreads();                 // A ready

        f32x4 acc00 = {}, acc01 = {}, acc10 = {}, acc11 = {};
#pragma unroll
        for (int kk = 0; kk < KS; ++kk) {
            f16x8 a0 = *(const f16x8*)&A[(rowbase + lrow + kk) * 40 + kgrp * 8];
            f16x8 a1 = *(const f16x8*)&A[(rowbase + 16 + lrow + kk) * 40 + kgrp * 8];
            f16x8 b0 = *(const f16x8*)&Wt[(kk * CH + lrow) * 40 + kgrp * 8];
            f16x8 b1 = *(const f16x8*)&Wt[(kk * CH + 16 + lrow) * 40 + kgrp * 8];
            acc00 = __builtin_amdgcn_mfma_f32_16x16x32_f16(a0, b0, acc00, 0, 0, 0);
            acc01 = __builtin_amdgcn_mfma_f32_16x16x32_f16(a0, b1, acc01, 0, 0, 0);
            acc10 = __builtin_amdgcn_mfma_f32_16x16x32_f16(a1, b0, acc10, 0, 0, 0);
            acc11 = __builtin_amdgcn_mfma_f32_16x16x32_f16(a1, b1, acc11, 0, 0, 0);
        }

        int tsub  = tb0 + j * BM;
        int rbase = rowbase + ((lane >> 4) << 2);
#pragma unroll
        for (int reg = 0; reg < 4; ++reg) {
            int t = tsub + rbase + reg;
            if (t < TOUT) {
                float* o = &out[((size_t)b * TOUT + t) * NF];
                o[col0]      = sv * acc00[reg] + bc0;
                o[col0 + 16] = sv * acc01[reg] + bc1;
            }
            int t1 = t + 16;
            if (t1 < TOUT) {
                float* o = &out[((size_t)b * TOUT + t1) * NF];
                o[col0]      = sv * acc10[reg] + bc0;
                o[col0 + 16] = sv * acc11[reg] + bc1;
            }
        }
    }
}

// ===================== FALLBACK path (round-1, proven 108 µs) =====================
__global__ __launch_bounds__(256) void chsum_kernel(const float* __restrict__ x,
                                                    float* __restrict__ ws) {
    __shared__ float tot[CH];
    int tid = threadIdx.x;
    if (tid < CH) tot[tid] = 0.f;
    __syncthreads();
    size_t idx4   = (size_t)blockIdx.x * blockDim.x + tid;
    size_t n4     = (size_t)NB * T * CH / 4;
    size_t stride = (size_t)gridDim.x * blockDim.x;
    int c0 = (int)((idx4 * 4) & (CH - 1));
    float s0 = 0.f, s1 = 0.f, s2 = 0.f, s3 = 0.f;
    const float4* x4 = (const float4*)x;
    for (size_t i = idx4; i < n4; i += stride) {
        float4 v = x4[i];
        s0 += v.x; s1 += v.y; s2 += v.z; s3 += v.w;
    }
    atomicAdd(&tot[c0 + 0], s0);
    atomicAdd(&tot[c0 + 1], s1);
    atomicAdd(&tot[c0 + 2], s2);
    atomicAdd(&tot[c0 + 3], s3);
    __syncthreads();
    if (tid < CH) atomicAdd(&ws[tid], tot[tid]);
}

__global__ __launch_bounds__(256) void scalar_kernel(const float* __restrict__ x,
                                                     const float* __restrict__ Wconv,
                                                     const float* __restrict__ bconv,
                                                     const float* __restrict__ Wdef,
                                                     float* __restrict__ ws) {
    __shared__ float hb[4][CH], tb[4][CH];
    __shared__ float partial[256];
    int tid = threadIdx.x;
    if (tid < 128) {
        int j = tid >> 5, c = tid & 31;
        float s = 0.f;
        for (int b = 0; b < NB; ++b) s += x[((size_t)b * T + j) * CH + c];
        hb[j][c] = s;
    } else {
        int p = tid - 128; int j = p >> 5, c = p & 31;
        float s = 0.f;
        for (int b = 0; b < NB; ++b) s += x[((size_t)b * T + (T - 4 + j)) * CH + c];
        tb[j][c] = s;
    }
    __syncthreads();
    float term = 0.f;
    if (tid < KS * CH) {
        int k = tid >> 5, c = tid & 31;
        float wf = 0.f;
        const float* wp = &Wconv[(size_t)tid * NF];
        for (int f = 0; f < NF; ++f) wf += wp[f];
        float S = ws[c];
        for (int j = 0; j < k; ++j) S -= hb[j][c];
        for (int j = k; j < 4; ++j) S -= tb[j][c];
        term = wf * S;
    }
    partial[tid] = term;
    __syncthreads();
    for (int off = 128; off > 0; off >>= 1) {
        if (tid < off) partial[tid] += partial[tid + off];
        __syncthreads();
    }
    if (tid == 0) {
        float sum_b = 0.f;
        for (int f = 0; f < NF; ++f) sum_b += bconv[f];
        float mean_off = partial[0] / (float)((size_t)NB * TOUT * NF) + sum_b / (float)NF;
        float s = 0.f;
        for (int k = 0; k < KS; ++k) {
            float pn = mean_off + (float)(k - 2);
            s += Wdef[k] * fmaxf(0.f, 1.f - fabsf(pn));
        }
        ws[CH] = s;
    }
}

__global__ __launch_bounds__(256) void conv_kernel(const float* __restrict__ x,
                                                   const float* __restrict__ Wconv,
                                                   const float* __restrict__ bconv,
                                                   const float* __restrict__ ws,
                                                   float* __restrict__ out) {
    __shared__ _Float16 A[(BM + 4) * 40];
    __shared__ _Float16 Wt[KS * CH * 40];

    int tid = threadIdx.x;
    int b   = blockIdx.y;
    int t0  = blockIdx.x * BM;

    const int AROWS = BM + 4;
    {
        int c0 = (tid & 7) * 4;
        for (int r = (tid >> 3); r < AROWS; r += 32) {
            int t = t0 + r;
            float4 v = make_float4(0.f, 0.f, 0.f, 0.f);
            if (t < T) v = *(const float4*)&x[((size_t)b * T + t) * CH + c0];
            *(f16x4*)&A[r * 40 + c0] = cvt4(v);
        }
    }
    if (tid < KS * CH) {
        int k = tid >> 5, c = tid & 31;
        const float* wp = &Wconv[(size_t)tid * NF];
        for (int f = 0; f < NF; ++f)
            Wt[(k * CH + f) * 40 + c] = (_Float16)wp[f];
    }
    __syncthreads();

    int lane = tid & 63;
    int wave = tid >> 6;
    int rowbase = wave * 32;
    int lrow = lane & 15;
    int kgrp = lane >> 4;

    f32x4 acc00 = {}, acc01 = {}, acc10 = {}, acc11 = {};
#pragma unroll
    for (int kk = 0; kk < KS; ++kk) {
        f16x8 a0 = *(const f16x8*)&A[(rowbase + lrow + kk) * 40 + kgrp * 8];
        f16x8 a1 = *(const f16x8*)&A[(rowbase + 16 + lrow + kk) * 40 + kgrp * 8];
        f16x8 b0 = *(const f16x8*)&Wt[(kk * CH + lrow) * 40 + kgrp * 8];
        f16x8 b1 = *(const f16x8*)&Wt[(kk * CH + 16 + lrow) * 40 + kgrp * 8];
        acc00 = __builtin_amdgcn_mfma_f32_16x16x32_f16(a0, b0, acc00, 0, 0, 0);
        acc01 = __builtin_amdgcn_mfma_f32_16x16x32_f16(a0, b1, acc01, 0, 0, 0);
        acc10 = __builtin_amdgcn_mfma_f32_16x16x32_f16(a1, b0, acc10, 0, 0, 0);
        acc11 = __builtin_amdgcn_mfma_f32_16x16x32_f16(a1, b1, acc11, 0, 0, 0);
    }

    float sv  = ws[CH];
    int col0  = lane & 15;
    float bc0 = bconv[col0], bc1 = bconv[col0 + 16];
    int rbase = rowbase + ((lane >> 4) << 2);
#pragma unroll
    for (int reg = 0; reg < 4; ++reg) {
        int t = t0 + rbase + reg;
        if (t < TOUT) {
            float* o = &out[((size_t)b * TOUT + t) * NF];
            o[col0]      = sv * acc00[reg] + bc0;
            o[col0 + 16] = sv * acc01[reg] + bc1;
        }
        int t1 = t + 16;
        if (t1 < TOUT) {
            float* o = &out[((size_t)b * TOUT + t1) * NF];
            o[col0]      = sv * acc10[reg] + bc0;
            o[col0 + 16] = sv * acc11[reg] + bc1;
        }
    }
}

extern "C" void kernel_launch(void* const* d_in, const int* in_sizes, int n_in,
                              void* d_out, int out_size, void* d_ws, size_t ws_size,
                              hipStream_t stream) {
    const float* x     = (const float*)d_in[0];
    const float* Wconv = (const float*)d_in[1];
    const float* bconv = (const float*)d_in[2];
    const float* Wdef  = (const float*)d_in[3];
    float* out = (float*)d_out;
    float* ws  = (float*)d_ws;

    hipMemsetAsync(ws, 0, 256, stream);   // sums + counter zeroed every call

    int nb = 0;
    (void)hipOccupancyMaxActiveBlocksPerMultiprocessor(&nb, mono2_kernel, 256, 0);

    if (nb >= 4) {
        mono2_kernel<<<dim3(NBLKM), dim3(256), 0, stream>>>(x, Wconv, bconv, Wdef, ws, out);
    } else {
        chsum_kernel<<<dim3(2048), dim3(256), 0, stream>>>(x, ws);
        scalar_kernel<<<dim3(1), dim3(256), 0, stream>>>(x, Wconv, bconv, Wdef, ws);
        dim3 grid((TOUT + BM - 1) / BM, NB);
        conv_kernel<<<grid, dim3(256), 0, stream>>>(x, Wconv, bconv, ws, out);
    }
}